// Round 2
// baseline (488.876 us; speedup 1.0000x reference)
//
#include <hip/hip_runtime.h>

// VQ: B=8, C_IN=1024, T=8192, K=1024, D=8
#define B_   8
#define C_   1024
#define T_   8192
#define K_   1024
#define D_   8
#define CT_  (C_ * T_)            // 8388608
#define BT_  (B_ * T_)            // 65536
#define OUTN_ ((size_t)B_ * CT_)  // 67108864 (output 0 elements)

// ---------------------------------------------------------------------------
// Prologue: wT[c][d] = in_w[d][c]  (contiguous 32 B rows -> s_load)
//           nrm[k]   = 0.5*||cb_k||^2 - in_b . cb_k   (bias folded in)
// ---------------------------------------------------------------------------
__global__ __launch_bounds__(256) void vq_prep(
    const float* __restrict__ in_w, const float* __restrict__ in_b,
    const float* __restrict__ cb, float* __restrict__ wT,
    float* __restrict__ nrm)
{
    const int i = blockIdx.x * 256 + threadIdx.x;
    if (i < C_ * D_) {
        const int d = i >> 10;
        const int c = i & (C_ - 1);
        wT[c * D_ + d] = in_w[i];
    }
    if (i < K_) {
        float s = 0.0f, q = 0.0f;
#pragma unroll
        for (int d = 0; d < D_; ++d) {
            const float w = cb[i * D_ + d];
            s = fmaf(w, w, s);
            q = fmaf(in_b[d], w, q);
        }
        nrm[i] = 0.5f * s - q;
    }
}

// ---------------------------------------------------------------------------
// Fused encode + argmin + decode.
// v3: 512-thread blocks (8 waves), t-tile = 128, grid = 512, LDS 68 KB ->
// TWO blocks per CU (one block's reduce/argmin/barriers overlap the other's
// HBM streaming).  CRITICAL: the encoder projection is computed in a fp
// order BIT-IDENTICAL to the verified v1 kernel: 16 partials of 64
// sequential channels each (each wave computes chunks 2wu and 2wu+1 with
// v1's exact fmaf chain), then reduced in ascending chunk order.  Distance,
// tie-break scan order and decode arithmetic are likewise order-preserving,
// so ids/out are bitwise equal to the passing v1 run.
// LDS: s_part[16][1024] (row-contiguous per-wave access -> conflict-free;
// 2 lanes/bank aliasing is free on gfx950), s_enc[16][64]; argmin val/idx
// and zq rows alias the dead s_part plane.
// ---------------------------------------------------------------------------
#define NW_    8      // waves per block
#define TT_    2      // t's per lane
#define TILE_  128    // t-tile per block
#define NCH_   16     // 64-channel chunks (v1 partial granularity)

__global__ __launch_bounds__(512, 4) void vq_fused(
    const float* __restrict__ z, const float* __restrict__ wT,
    const float* __restrict__ nrm, const float* __restrict__ cb,
    const float* __restrict__ out_w, const float* __restrict__ out_b,
    float* __restrict__ out, float* __restrict__ ids_f)
{
    __shared__ float s_part[NCH_ * 1024];  // 64 KB  partial planes (aliased)
    __shared__ float s_enc[16 * 64];       // 4 KB   enc[row=tt*8+d][lane]

    float* s_val = s_part;                 // [8][128]   (plane dead by then)
    int*   s_idx = (int*)(s_part + 1024);  // [8][128]
    float* s_zq  = s_part + 2048;          // [128] stride-9 rows (4.5 KB)

    const int tid = threadIdx.x;
    const int wu  = __builtin_amdgcn_readfirstlane(tid >> 6); // uniform wave id
    const int l   = tid & 63;
    const int blk = blockIdx.x;
    const int b   = blk >> 6;                 // 64 t-tiles per b
    const int t0  = (blk & 63) << 7;          // 128-t tile base
    const int c0  = wu << 7;                  // wave's 128-c / 128-k base

    // ---- phase A: TWO 64-channel partials per wave, v1-exact fmaf order ----
    float acc[2][TT_][D_];                    // [chunk h][tt][d]
#pragma unroll
    for (int h = 0; h < 2; ++h)
#pragma unroll
        for (int tt = 0; tt < TT_; ++tt)
#pragma unroll
            for (int d = 0; d < D_; ++d) acc[h][tt][d] = 0.0f;

    const float2* zp =
        (const float2*)(z + (size_t)b * CT_ + (size_t)c0 * T_ + t0) + l;
#pragma unroll
    for (int h = 0; h < 2; ++h) {
        for (int i = 0; i < 64; i += 4) {
            float2 zv[4];
#pragma unroll
            for (int u = 0; u < 4; ++u)
                zv[u] = zp[(size_t)(h * 64 + i + u) * (T_ / 2)];
#pragma unroll
            for (int u = 0; u < 4; ++u) {
                const float* wr = wT + (size_t)(c0 + h * 64 + i + u) * D_;
#pragma unroll
                for (int d = 0; d < D_; ++d) {
                    const float wv = wr[d];
                    acc[h][0][d] = fmaf(zv[u].x, wv, acc[h][0][d]);
                    acc[h][1][d] = fmaf(zv[u].y, wv, acc[h][1][d]);
                }
            }
        }
    }
    // stage partials: row = tt*8+d, col = chunk*64 + l  (row-contig -> CF)
#pragma unroll
    for (int h = 0; h < 2; ++h)
#pragma unroll
        for (int tt = 0; tt < TT_; ++tt)
#pragma unroll
            for (int d = 0; d < D_; ++d)
                s_part[(tt * D_ + d) * 1024 + (2 * wu + h) * 64 + l] =
                    acc[h][tt][d];
    __syncthreads();

    // ---- reduce 16 chunk-partials in ascending order (v1-exact) ----
#pragma unroll
    for (int r = 0; r < 2; ++r) {
        const int p = tid + r * 512;
        const int row = p >> 6, l2 = p & 63;   // row uniform per wave
        float s = 0.0f;
#pragma unroll
        for (int ww = 0; ww < NCH_; ++ww)
            s += s_part[row * 1024 + ww * 64 + l2];
        s_enc[p] = s;
    }
    __syncthreads();

    // ---- phase B: argmin over wave's 128-k chunk for lane's 2 t's ----
    float e[TT_][D_];
#pragma unroll
    for (int tt = 0; tt < TT_; ++tt)
#pragma unroll
        for (int d = 0; d < D_; ++d)
            e[tt][d] = s_enc[(tt * D_ + d) * 64 + l];

    float best[TT_];
    int   bi[TT_];
#pragma unroll
    for (int tt = 0; tt < TT_; ++tt) { best[tt] = 3.4e38f; bi[tt] = 0; }

    for (int j = 0; j < 128; ++j) {
        const int k = c0 + j;
        const float* cr = cb + (size_t)k * D_;   // uniform -> s_load
        const float nk = nrm[k];                 // uniform -> s_load
#pragma unroll
        for (int tt = 0; tt < TT_; ++tt) {
            float s = nk;
#pragma unroll
            for (int d = 0; d < D_; ++d) s = fmaf(-e[tt][d], cr[d], s);
            if (s < best[tt]) { best[tt] = s; bi[tt] = k; }  // first min wins
        }
    }
#pragma unroll
    for (int tt = 0; tt < TT_; ++tt) {
        s_val[wu * TILE_ + 2 * l + tt] = best[tt];
        s_idx[wu * TILE_ + 2 * l + tt] = bi[tt];
    }
    __syncthreads();

    // ---- cross-wave argmin scan (ww ascending == k ascending); zq gather ----
    if (tid < TILE_) {
        float bv = s_val[tid];
        int   bb = s_idx[tid];
#pragma unroll
        for (int ww = 1; ww < NW_; ++ww) {
            const float v = s_val[ww * TILE_ + tid];
            if (v < bv) { bv = v; bb = s_idx[ww * TILE_ + tid]; }
        }
        ids_f[blk * TILE_ + tid] = (float)bb;
        const float4* cp = (const float4*)(cb + (size_t)bb * D_);
        const float4 a = cp[0], q = cp[1];
        float* zr = s_zq + tid * 9;
        zr[0] = a.x; zr[1] = a.y; zr[2] = a.z; zr[3] = a.w;
        zr[4] = q.x; zr[5] = q.y; zr[6] = q.z; zr[7] = q.w;
    }
    __syncthreads();

    // ---- decode: wave writes its 128-c chunk, float2 stores ----
    float r2[TT_][D_];
#pragma unroll
    for (int tt = 0; tt < TT_; ++tt)
#pragma unroll
        for (int d = 0; d < D_; ++d)
            r2[tt][d] = s_zq[(2 * l + tt) * 9 + d];

    float2* op = (float2*)(out + (size_t)b * CT_ + (size_t)c0 * T_ + t0) + l;
#pragma unroll 4
    for (int j = 0; j < 128; ++j) {
        const int c = c0 + j;
        const float* wr = out_w + (size_t)c * D_;  // uniform -> s_load
        const float bias = out_b[c];               // uniform -> s_load
        float2 o;
        o.x = bias; o.y = bias;
#pragma unroll
        for (int d = 0; d < D_; ++d) {
            const float wv = wr[d];
            o.x = fmaf(r2[0][d], wv, o.x);
            o.y = fmaf(r2[1][d], wv, o.y);
        }
        op[(size_t)j * (T_ / 2)] = o;
    }
}

extern "C" void kernel_launch(void* const* d_in, const int* in_sizes, int n_in,
                              void* d_out, int out_size, void* d_ws, size_t ws_size,
                              hipStream_t stream) {
    const float* z    = (const float*)d_in[0];
    const float* in_w = (const float*)d_in[1];
    const float* in_b = (const float*)d_in[2];
    const float* cb   = (const float*)d_in[3];
    const float* ow   = (const float*)d_in[4];
    const float* ob   = (const float*)d_in[5];

    float* out   = (float*)d_out;
    float* ids_f = out + OUTN_;      // output 1 (ids as float) follows output 0

    float* wT  = (float*)d_ws;       // 8192 floats
    float* nrm = wT + C_ * D_;       // 1024 floats

    vq_prep<<<32, 256, 0, stream>>>(in_w, in_b, cb, wT, nrm);
    vq_fused<<<512, 512, 0, stream>>>(z, wT, nrm, cb, ow, ob, out, ids_f);
}